// Round 1
// baseline (110.430 us; speedup 1.0000x reference)
//
#include <hip/hip_runtime.h>
#include <hip/hip_bf16.h>

// SpectralConv2d: B=8, CIN=COUT=32, N=4096, M1=M2=16 -> modes 32x x 31y
// k1[x] = x<16 ? x : x-32 ; k2[y] = y<16 ? y : y-31
//
// ws layout (floats):
//   u_ft    [b][x][c][y][2]  : 8*32*32*31*2 = 507904
//   out_full[b][x][c][y][2]  : 507904
// total 4.06 MB.

#define NPTS 4096
#define TDIM 128
#define TWO_PI 6.283185307179586f

typedef __attribute__((ext_vector_type(8))) short bf16x8;   // 8 bf16 = 4 VGPR
typedef __attribute__((ext_vector_type(4))) float f32x4;

__device__ __forceinline__ unsigned int f2bf(float f) {
  unsigned int v = __float_as_uint(f);
  v += 0x7FFFu + ((v >> 16) & 1u);   // RNE
  return v >> 16;
}
__device__ __forceinline__ unsigned int pack2(float a, float b) {
  return f2bf(a) | (f2bf(b) << 16);
}

// ---------------------------------------------------------------------------
// Phase 1: u_ft[b][x][c][y][{re,im}] = sum_n u[b][c][n] * exp(-2pi i (x0*k1x + x1*k2y))
// GEMM per (b,x): A = u [32c x 4096n] bf16, B = basis^T stored [j=2y+comp][n] bf16,
// D[c][j] fp32.  MFMA 16x16x32, 4 waves: wave w -> cols 16w..16w+15, both m-tiles.
__global__ __launch_bounds__(256) void uft_kernel(
    const float* __restrict__ u, const float* __restrict__ x_in,
    float* __restrict__ u_ft) {
  const int x = blockIdx.x, b = blockIdx.y;
  const int tid = threadIdx.x;
  const int lane = tid & 63, wv = tid >> 6;

  __shared__ __align__(16) unsigned short u_bf[32 * 256];    // [c][kk], 512B rows, swizzled
  __shared__ __align__(16) unsigned short bas_bf[64 * 256];  // [j][kk], 512B rows, swizzled

  const float k1x = (x < 16) ? (float)x : (float)(x - 32);

  f32x4 acc0 = {0.f, 0.f, 0.f, 0.f};
  f32x4 acc1 = {0.f, 0.f, 0.f, 0.f};

  const int colw = lane & 15;
  const int kq = lane >> 4;          // 0..3
  const int arow1 = colw + 16;
  const int brow = wv * 16 + colw;   // basis row j = 2y+comp (0..63)

  for (int n0 = 0; n0 < NPTS; n0 += 256) {
    __syncthreads();   // previous MFMA reads done before restaging

    // --- stage u -> bf16 LDS (tasks: 32c x 32 nn-octets) ---
    #pragma unroll
    for (int it = 0; it < 4; ++it) {
      int task = tid + it * 256;
      int c = task >> 5;
      int nn8 = (task & 31) << 3;
      const float4* src = (const float4*)&u[(size_t)(b * 32 + c) * NPTS + n0 + nn8];
      float4 f0 = src[0], f1 = src[1];
      uint4 p;
      p.x = pack2(f0.x, f0.y);
      p.y = pack2(f0.z, f0.w);
      p.z = pack2(f1.x, f1.y);
      p.w = pack2(f1.z, f1.w);
      *(uint4*)((char*)u_bf + c * 512 + ((nn8 * 2) ^ ((c & 7) << 4))) = p;
    }

    // --- generate basis rows: j=2y -> cos(-th)=cos(th), j=2y+1 -> sin(-th) ---
    #pragma unroll
    for (int it = 0; it < 4; ++it) {
      int task = tid + it * 256;
      int y = task >> 5;                  // 0..31 (31 = zero pad)
      int nn8 = (task & 31) << 3;
      uint4 pc = {0u, 0u, 0u, 0u}, ps = {0u, 0u, 0u, 0u};
      if (y < 31) {
        float k2y = (y < 16) ? (float)y : (float)(y - 31);
        const float2* xp = (const float2*)&x_in[(size_t)(b * NPTS + n0 + nn8) * 2];
        float th[8];
        #pragma unroll
        for (int i = 0; i < 8; ++i) {
          float2 xv = xp[i];
          th[i] = -TWO_PI * (xv.x * k1x + xv.y * k2y);
        }
        pc.x = pack2(__cosf(th[0]), __cosf(th[1]));
        pc.y = pack2(__cosf(th[2]), __cosf(th[3]));
        pc.z = pack2(__cosf(th[4]), __cosf(th[5]));
        pc.w = pack2(__cosf(th[6]), __cosf(th[7]));
        ps.x = pack2(__sinf(th[0]), __sinf(th[1]));
        ps.y = pack2(__sinf(th[2]), __sinf(th[3]));
        ps.z = pack2(__sinf(th[4]), __sinf(th[5]));
        ps.w = pack2(__sinf(th[6]), __sinf(th[7]));
      }
      int rc = 2 * y, rs = 2 * y + 1;
      *(uint4*)((char*)bas_bf + rc * 512 + ((nn8 * 2) ^ ((rc & 7) << 4))) = pc;
      *(uint4*)((char*)bas_bf + rs * 512 + ((nn8 * 2) ^ ((rs & 7) << 4))) = ps;
    }
    __syncthreads();

    // --- MFMA: 8 k-steps of 32 ---
    #pragma unroll
    for (int ks = 0; ks < 8; ++ks) {
      int kb = ks * 64 + kq * 16;
      bf16x8 a0 = *(bf16x8*)((char*)u_bf + colw * 512 + (kb ^ ((colw & 7) << 4)));
      bf16x8 a1 = *(bf16x8*)((char*)u_bf + arow1 * 512 + (kb ^ ((arow1 & 7) << 4)));
      bf16x8 bb = *(bf16x8*)((char*)bas_bf + brow * 512 + (kb ^ ((brow & 7) << 4)));
      acc0 = __builtin_amdgcn_mfma_f32_16x16x32_bf16(a0, bb, acc0, 0, 0, 0);
      acc1 = __builtin_amdgcn_mfma_f32_16x16x32_bf16(a1, bb, acc1, 0, 0, 0);
    }
  }

  // epilogue: D col = lane&15 -> j (this wave's 16-col tile), row = kq*4+r -> c
  int j = brow;
  int y = j >> 1, comp = j & 1;
  if (y < 31) {
    int c0 = kq * 4;
    #pragma unroll
    for (int r = 0; r < 4; ++r) {
      u_ft[(size_t)((b * 32 + x) * 32 + c0 + r) * 62 + y * 2 + comp] = acc0[r];
      u_ft[(size_t)((b * 32 + x) * 32 + c0 + r + 16) * 62 + y * 2 + comp] = acc1[r];
    }
  }
}

// ---------------------------------------------------------------------------
// Phase 2: out_ft[b][o][x][y] = emb_sel[b,m1,y] * sum_i u_ft[b,i,x,y]*w_sel_c[i,o,m1,y]
// plus Hermitian extension into out_full[b][x][c][y][2] (y 0..30).
__global__ __launch_bounds__(512) void apply_kernel(
    const float* __restrict__ t, const float* __restrict__ w_freq,
    const float* __restrict__ b_freq, const float* __restrict__ w1,
    const float* __restrict__ w2, const float* __restrict__ u_ft,
    float* __restrict__ out_full) {
  const int x = blockIdx.x, b = blockIdx.y;
  const int tid = threadIdx.x;
  const int m1 = x & 15, sel = x >> 4;

  __shared__ float uf_s[32][16][2];
  __shared__ float emb_s[16][2];

  for (int idx = tid; idx < 32 * 32; idx += 512) {
    int i = idx >> 5, r = idx & 31;
    uf_s[i][r >> 1][r & 1] = u_ft[(size_t)((b * 32 + x) * 32 + i) * 62 + r];
  }
  if (tid < 32) {
    // h reshape [B][m1][m2][w][p]: flat = ((m1*16+y)*2 + w)*2 + p
    int y = tid >> 1, p = tid & 1;
    int jj = ((m1 * 16 + y) * 2 + sel) * 2 + p;
    float s = b_freq[jj];
    for (int k = 0; k < TDIM; ++k) s += t[b * TDIM + k] * w_freq[k * 1024 + jj];
    emb_s[y][p] = s;
  }
  __syncthreads();

  int o = tid >> 4, y = tid & 15;
  const float* wsel = sel ? w2 : w1;
  float fr = 0.f, fi = 0.f;
  #pragma unroll 4
  for (int i = 0; i < 32; ++i) {
    float2 w = *(const float2*)&wsel[(size_t)(((i * 32 + o) * 16 + m1) * 16 + y) * 2];
    float ur = uf_s[i][y][0], ui = uf_s[i][y][1];
    fr += ur * w.x - ui * w.y;
    fi += ur * w.y + ui * w.x;
  }
  float er = emb_s[y][0], ei = emb_s[y][1];
  float orr = fr * er - fi * ei;
  float oii = fr * ei + fi * er;
  size_t mo = (size_t)((b * 32 + x) * 32 + o) * 62 + y * 2;
  out_full[mo] = orr;
  out_full[mo + 1] = oii;
  if (y > 0) {
    // out_full[b, c, 31-x, 31-y] = conj(out_ft[b, c, x, y])
    size_t cj = (size_t)((b * 32 + (31 - x)) * 32 + o) * 62 + (31 - y) * 2;
    out_full[cj] = orr;
    out_full[cj + 1] = -oii;
  }
}

// ---------------------------------------------------------------------------
// Phase 3: Y[b][c][n] = sum_{x,y} ( or*cos(+th) - oi*sin(+th) ),
// GEMM per (b, 64-n tile): A = O' [32c x K], B^T = basis [n][k], K chunked by x (64 k).
__global__ __launch_bounds__(256) void inv_kernel(
    const float* __restrict__ out_full, const float* __restrict__ x_out,
    float* __restrict__ Y) {
  const int nt = blockIdx.x, b = blockIdx.y;
  const int n0 = nt * 64;
  const int tid = threadIdx.x;
  const int lane = tid & 63, wv = tid >> 6;

  __shared__ __align__(16) unsigned short A_bf[32 * 64];   // [c][kk], 128B rows, swizzled
  __shared__ __align__(16) unsigned short B_bf[64 * 64];   // [n][kk], 128B rows, swizzled

  const int colw = lane & 15;
  const int kq = lane >> 4;
  const int arow1 = colw + 16;
  const int brow = wv * 16 + colw;   // n_local

  f32x4 acc0 = {0.f, 0.f, 0.f, 0.f};
  f32x4 acc1 = {0.f, 0.f, 0.f, 0.f};

  for (int x = 0; x < 32; ++x) {
    __syncthreads();
    const float k1x = (x < 16) ? (float)x : (float)(x - 32);

    // stage A: A[c][2y]=or, A[c][2y+1]=oi  (y=31 pad -> 0)
    #pragma unroll
    for (int it = 0; it < 4; ++it) {
      int idx = tid + it * 256;       // 0..1023
      int c = idx >> 5, p = idx & 31;
      unsigned int pk = 0u;
      if (p < 31) {
        float2 v = *(const float2*)&out_full[(size_t)((b * 32 + x) * 32 + c) * 62 + p * 2];
        pk = pack2(v.x, v.y);
      }
      *(unsigned int*)((char*)A_bf + c * 128 + ((p * 4) ^ ((c & 7) << 4))) = pk;
    }
    // stage B: B[n][2y]=cos(th), B[n][2y+1]=-sin(th)
    #pragma unroll
    for (int it = 0; it < 8; ++it) {
      int idx = tid + it * 256;       // 0..2047
      int n = idx >> 5, yy = idx & 31;
      unsigned int pk = 0u;
      if (yy < 31) {
        float k2y = (yy < 16) ? (float)yy : (float)(yy - 31);
        float2 xv = *(const float2*)&x_out[(size_t)(b * NPTS + n0 + n) * 2];
        float th = TWO_PI * (xv.x * k1x + xv.y * k2y);
        pk = pack2(__cosf(th), -__sinf(th));
      }
      *(unsigned int*)((char*)B_bf + n * 128 + ((yy * 4) ^ ((n & 7) << 4))) = pk;
    }
    __syncthreads();

    #pragma unroll
    for (int ks = 0; ks < 2; ++ks) {
      int kb = ks * 64 + kq * 16;
      bf16x8 a0 = *(bf16x8*)((char*)A_bf + colw * 128 + (kb ^ ((colw & 7) << 4)));
      bf16x8 a1 = *(bf16x8*)((char*)A_bf + arow1 * 128 + (kb ^ ((arow1 & 7) << 4)));
      bf16x8 bb = *(bf16x8*)((char*)B_bf + brow * 128 + (kb ^ ((brow & 7) << 4)));
      acc0 = __builtin_amdgcn_mfma_f32_16x16x32_bf16(a0, bb, acc0, 0, 0, 0);
      acc1 = __builtin_amdgcn_mfma_f32_16x16x32_bf16(a1, bb, acc1, 0, 0, 0);
    }
  }

  int n = n0 + brow;       // D col = lane&15 within this wave's n-tile
  int c0 = kq * 4;
  #pragma unroll
  for (int r = 0; r < 4; ++r) {
    Y[(size_t)(b * 32 + c0 + r) * NPTS + n] = acc0[r];
    Y[(size_t)(b * 32 + c0 + r + 16) * NPTS + n] = acc1[r];
  }
}

// ---------------------------------------------------------------------------
extern "C" void kernel_launch(void* const* d_in, const int* in_sizes, int n_in,
                              void* d_out, int out_size, void* d_ws, size_t ws_size,
                              hipStream_t stream) {
  const float* u      = (const float*)d_in[0];
  const float* x_in   = (const float*)d_in[1];
  const float* x_out  = (const float*)d_in[2];
  const float* t      = (const float*)d_in[3];
  const float* w_freq = (const float*)d_in[4];
  const float* b_freq = (const float*)d_in[5];
  const float* w1     = (const float*)d_in[6];
  const float* w2     = (const float*)d_in[7];
  float* Y = (float*)d_out;

  float* u_ft = (float*)d_ws;            // 507904 floats
  float* out_full = u_ft + 507904;       // 507904 floats  (total ws: 4.06 MB)

  uft_kernel<<<dim3(32, 8), 256, 0, stream>>>(u, x_in, u_ft);
  apply_kernel<<<dim3(32, 8), 512, 0, stream>>>(t, w_freq, b_freq, w1, w2, u_ft, out_full);
  inv_kernel<<<dim3(64, 8), 256, 0, stream>>>(out_full, x_out, Y);
}

// Round 2
// 98.769 us; speedup vs baseline: 1.1181x; 1.1181x over previous
//
#include <hip/hip_runtime.h>
#include <hip/hip_bf16.h>

// SpectralConv2d: B=8, CIN=COUT=32, N=4096, modes 32x x 31y
// Factorized basis: exp(i(th1+th2)) = E1[n,x]*E2[n,y].
// E2 tables precomputed (bf16 cos|sin packed in uint32), E1 computed in-kernel.
//
// ws layout (4-byte slots):
//   E2in  [b][y][n]          : 8*32*4096 = 1048576
//   E2out [b][y][n]          : 1048576
//   P_uft [s=4][b][x][c][62] : 4*507904 = 2031616   (also reused as inv partial)
//   out_full [b][x][c][62]   : 507904
// total 4,636,672 slots = 18.55 MB

#define NPTS 4096
#define TDIM 128
#define TWO_PI 6.283185307179586f

typedef __attribute__((ext_vector_type(8))) short bf16x8;
typedef __attribute__((ext_vector_type(4))) float f32x4;

__device__ __forceinline__ unsigned int f2bf(float f) {
  unsigned int v = __float_as_uint(f);
  v += 0x7FFFu + ((v >> 16) & 1u);   // RNE
  return v >> 16;
}
__device__ __forceinline__ unsigned int pack2(float a, float b) {
  return f2bf(a) | (f2bf(b) << 16);
}
__device__ __forceinline__ float bflo(unsigned int u) { return __uint_as_float(u << 16); }
__device__ __forceinline__ float bfhi(unsigned int u) { return __uint_as_float(u & 0xFFFF0000u); }

// ---------------------------------------------------------------------------
// Prep: E2 tables.  E2[b][y][n] = pack(cos(2pi*x1*k2y), sin(2pi*x1*k2y)); y=31 -> 0.
__global__ __launch_bounds__(256) void prep_kernel(
    const float* __restrict__ x_in, const float* __restrict__ x_out,
    unsigned int* __restrict__ E2in, unsigned int* __restrict__ E2out) {
  int lin = blockIdx.x * 256 + threadIdx.x;   // 524288 tasks, 4 n each
  int tbl = lin >> 18;
  int rem = lin & 262143;
  int b = rem >> 15;
  int rem2 = rem & 32767;
  int y = rem2 >> 10;
  int n4 = (rem2 & 1023) << 2;
  const float* xs = tbl ? x_out : x_in;
  unsigned int* dst = tbl ? E2out : E2in;
  uint4 p = {0u, 0u, 0u, 0u};
  if (y < 31) {
    float k2y = (y < 16) ? (float)y : (float)(y - 31);
    unsigned int* pp = &p.x;
    #pragma unroll
    for (int i = 0; i < 4; ++i) {
      float x1 = xs[(size_t)(b * NPTS + n4 + i) * 2 + 1];
      float th = TWO_PI * x1 * k2y;
      pp[i] = pack2(__cosf(th), __sinf(th));
    }
  }
  *(uint4*)&dst[((b * 32 + y) << 12) + n4] = p;
}

// ---------------------------------------------------------------------------
// Phase 1 (split-K by 4): per (b,x,s): A = u bf16 [32c x 1024n],
// B rows j=2y+comp built by E1*E2 combine. D -> P_uft[s].
__global__ __launch_bounds__(256) void uft_kernel(
    const float* __restrict__ u, const float* __restrict__ x_in,
    const unsigned int* __restrict__ E2in, float* __restrict__ P) {
  const int bid = blockIdx.x;        // 1024
  const int b = bid & 7;             // XCD pin: all blocks of b on one XCD
  const int inner = bid >> 3;        // 0..127
  const int x = inner & 31;
  const int s = inner >> 5;          // k-split 0..3
  const int tid = threadIdx.x;
  const int lane = tid & 63, wv = tid >> 6;

  __shared__ __align__(16) unsigned short u_bf[32 * 256];    // 16KB, swizzled
  __shared__ __align__(16) unsigned short bas_bf[64 * 256];  // 32KB, swizzled

  const float k1x = (x < 16) ? (float)x : (float)(x - 32);

  f32x4 acc0 = {0.f, 0.f, 0.f, 0.f};
  f32x4 acc1 = {0.f, 0.f, 0.f, 0.f};

  const int colw = lane & 15;
  const int kq = lane >> 4;
  const int arow1 = colw + 16;
  const int brow = wv * 16 + colw;

  const int oct = tid & 31;   // n-octet owner
  const int yg = tid >> 5;    // 0..7

  for (int ch = 0; ch < 4; ++ch) {
    const int n0 = s * 1024 + ch * 256;
    __syncthreads();

    // stage u -> bf16 LDS
    #pragma unroll
    for (int it = 0; it < 4; ++it) {
      int task = tid + it * 256;
      int c = task >> 5;
      int nn8 = (task & 31) << 3;
      const float4* src = (const float4*)&u[(size_t)(b * 32 + c) * NPTS + n0 + nn8];
      float4 f0 = src[0], f1 = src[1];
      uint4 p;
      p.x = pack2(f0.x, f0.y);
      p.y = pack2(f0.z, f0.w);
      p.z = pack2(f1.x, f1.y);
      p.w = pack2(f1.z, f1.w);
      *(uint4*)((char*)u_bf + c * 512 + ((nn8 * 2) ^ ((c & 7) << 4))) = p;
    }

    // E1 (x-basis) for this thread's 8 n's: only 8 sincos pairs per chunk
    float c1[8], ns1[8];
    {
      const float2* xp = (const float2*)&x_in[(size_t)(b * NPTS + n0 + oct * 8) * 2];
      #pragma unroll
      for (int i = 0; i < 8; ++i) {
        float th = TWO_PI * xp[i].x * k1x;
        c1[i] = __cosf(th);
        ns1[i] = -__sinf(th);
      }
    }

    // basis combine: y = yg + 8k; rows 2y (re), 2y+1 (im)
    #pragma unroll
    for (int k = 0; k < 4; ++k) {
      int y = yg + 8 * k;
      const uint4* e2p = (const uint4*)&E2in[((b * 32 + y) << 12) + n0 + oct * 8];
      uint4 e0 = e2p[0], e1 = e2p[1];
      unsigned int ee[8] = {e0.x, e0.y, e0.z, e0.w, e1.x, e1.y, e1.z, e1.w};
      float re[8], im[8];
      #pragma unroll
      for (int i = 0; i < 8; ++i) {
        float c2 = bflo(ee[i]), s2 = bfhi(ee[i]);
        re[i] = fmaf(c1[i], c2, ns1[i] * s2);          // c1c2 - s1s2
        im[i] = fmaf(ns1[i], c2, -c1[i] * s2);         // -(s1c2 + c1s2)
      }
      uint4 pr, pi;
      pr.x = pack2(re[0], re[1]); pr.y = pack2(re[2], re[3]);
      pr.z = pack2(re[4], re[5]); pr.w = pack2(re[6], re[7]);
      pi.x = pack2(im[0], im[1]); pi.y = pack2(im[2], im[3]);
      pi.z = pack2(im[4], im[5]); pi.w = pack2(im[6], im[7]);
      int rc = 2 * y, rs = 2 * y + 1;
      int nb = oct * 16;
      *(uint4*)((char*)bas_bf + rc * 512 + (nb ^ ((rc & 7) << 4))) = pr;
      *(uint4*)((char*)bas_bf + rs * 512 + (nb ^ ((rs & 7) << 4))) = pi;
    }
    __syncthreads();

    #pragma unroll
    for (int ks = 0; ks < 8; ++ks) {
      int kb = ks * 64 + kq * 16;
      bf16x8 a0 = *(bf16x8*)((char*)u_bf + colw * 512 + (kb ^ ((colw & 7) << 4)));
      bf16x8 a1 = *(bf16x8*)((char*)u_bf + arow1 * 512 + (kb ^ ((arow1 & 7) << 4)));
      bf16x8 bb = *(bf16x8*)((char*)bas_bf + brow * 512 + (kb ^ ((brow & 7) << 4)));
      acc0 = __builtin_amdgcn_mfma_f32_16x16x32_bf16(a0, bb, acc0, 0, 0, 0);
      acc1 = __builtin_amdgcn_mfma_f32_16x16x32_bf16(a1, bb, acc1, 0, 0, 0);
    }
  }

  int j = brow, y = j >> 1, comp = j & 1;
  if (y < 31) {
    int c0 = kq * 4;
    float* Ps = P + (size_t)s * 507904;
    #pragma unroll
    for (int r = 0; r < 4; ++r) {
      Ps[(size_t)((b * 32 + x) * 32 + c0 + r) * 62 + y * 2 + comp] = acc0[r];
      Ps[(size_t)((b * 32 + x) * 32 + c0 + r + 16) * 62 + y * 2 + comp] = acc1[r];
    }
  }
}

// ---------------------------------------------------------------------------
// Phase 2: mode-wise complex matmul + emb conditioning + Hermitian extension.
// Reads the 4 split-K partials and sums (fused reduce).
__global__ __launch_bounds__(512) void apply_kernel(
    const float* __restrict__ t, const float* __restrict__ w_freq,
    const float* __restrict__ b_freq, const float* __restrict__ w1,
    const float* __restrict__ w2, const float* __restrict__ P,
    float* __restrict__ out_full) {
  const int x = blockIdx.x, b = blockIdx.y;
  const int tid = threadIdx.x;
  const int m1 = x & 15, sel = x >> 4;

  __shared__ float uf_s[32][16][2];
  __shared__ float emb_s[16][2];

  for (int idx = tid; idx < 32 * 32; idx += 512) {
    int i = idx >> 5, r = idx & 31;
    size_t base = (size_t)((b * 32 + x) * 32 + i) * 62 + r;
    uf_s[i][r >> 1][r & 1] = P[base] + P[base + 507904] + P[base + 2 * 507904] + P[base + 3 * 507904];
  }
  if (tid < 32) {
    int y = tid >> 1, p = tid & 1;
    int jj = ((m1 * 16 + y) * 2 + sel) * 2 + p;
    float s = b_freq[jj];
    for (int k = 0; k < TDIM; ++k) s += t[b * TDIM + k] * w_freq[k * 1024 + jj];
    emb_s[y][p] = s;
  }
  __syncthreads();

  int o = tid >> 4, y = tid & 15;
  const float* wsel = sel ? w2 : w1;
  float fr = 0.f, fi = 0.f;
  #pragma unroll 4
  for (int i = 0; i < 32; ++i) {
    float2 w = *(const float2*)&wsel[(size_t)(((i * 32 + o) * 16 + m1) * 16 + y) * 2];
    float ur = uf_s[i][y][0], ui = uf_s[i][y][1];
    fr += ur * w.x - ui * w.y;
    fi += ur * w.y + ui * w.x;
  }
  float er = emb_s[y][0], ei = emb_s[y][1];
  float orr = fr * er - fi * ei;
  float oii = fr * ei + fi * er;
  size_t mo = (size_t)((b * 32 + x) * 32 + o) * 62 + y * 2;
  out_full[mo] = orr;
  out_full[mo + 1] = oii;
  if (y > 0) {
    size_t cj = (size_t)((b * 32 + (31 - x)) * 32 + o) * 62 + (31 - y) * 2;
    out_full[cj] = orr;
    out_full[cj + 1] = -oii;
  }
}

// ---------------------------------------------------------------------------
// Phase 3 (x-loop split by 2): per (b, nt, xh): 16 x-iterations,
// B combine from E2out (LDS-cached) * in-kernel E1.  xh=0 -> Y, xh=1 -> P1.
__global__ __launch_bounds__(256) void inv_kernel(
    const float* __restrict__ out_full, const float* __restrict__ x_out,
    const unsigned int* __restrict__ E2out, float* __restrict__ Y,
    float* __restrict__ P1) {
  const int bid = blockIdx.x;        // 1024
  const int b = bid & 7;
  const int inner = bid >> 3;        // 0..127
  const int nt = inner & 63;
  const int xh = inner >> 6;
  const int n0 = nt * 64;
  const int tid = threadIdx.x;
  const int lane = tid & 63, wv = tid >> 6;

  __shared__ __align__(16) unsigned short A_bf[32 * 64];
  __shared__ __align__(16) unsigned short B_bf[64 * 64];
  __shared__ unsigned int e2s[32 * 65];   // [y][n], +1-ish pad via stride 65

  // stage E2out slice once per block
  #pragma unroll
  for (int it = 0; it < 8; ++it) {
    int idx = tid + it * 256;
    int y = idx >> 6, n = idx & 63;
    e2s[y * 65 + n] = E2out[((b * 32 + y) << 12) + n0 + n];
  }

  const int bn = tid >> 2;       // fixed B-row n per thread
  const int ygr = tid & 3;       // y-group (8 y's)
  const float x0 = x_out[(size_t)(b * NPTS + n0 + bn) * 2];

  const int colw = lane & 15;
  const int kq = lane >> 4;
  const int arow1 = colw + 16;
  const int brow = wv * 16 + colw;

  f32x4 acc0 = {0.f, 0.f, 0.f, 0.f};
  f32x4 acc1 = {0.f, 0.f, 0.f, 0.f};

  for (int xi = 0; xi < 16; ++xi) {
    const int x = xh * 16 + xi;
    __syncthreads();
    const float k1x = (x < 16) ? (float)x : (float)(x - 32);

    // stage A from out_full
    #pragma unroll
    for (int it = 0; it < 4; ++it) {
      int idx = tid + it * 256;
      int c = idx >> 5, p = idx & 31;
      unsigned int pk = 0u;
      if (p < 31) {
        float2 v = *(const float2*)&out_full[(size_t)((b * 32 + x) * 32 + c) * 62 + p * 2];
        pk = pack2(v.x, v.y);
      }
      *(unsigned int*)((char*)A_bf + c * 128 + ((p * 4) ^ ((c & 7) << 4))) = pk;
    }

    // stage B: row bn, 8 y's; combine E1(x)*E2(y)
    {
      float th1 = TWO_PI * x0 * k1x;
      float c1 = __cosf(th1), s1 = __sinf(th1);
      float ns1 = -s1, nc1 = -c1;
      #pragma unroll
      for (int k = 0; k < 8; ++k) {
        int y = ygr * 8 + k;
        unsigned int e = e2s[y * 65 + bn];
        float c2 = bflo(e), s2 = bfhi(e);
        float re = fmaf(c1, c2, ns1 * s2);    // cos(th1+th2)
        float im = fmaf(ns1, c2, nc1 * s2);   // -sin(th1+th2)
        *(unsigned int*)((char*)B_bf + bn * 128 + ((y * 4) ^ ((bn & 7) << 4))) = pack2(re, im);
      }
    }
    __syncthreads();

    #pragma unroll
    for (int ks = 0; ks < 2; ++ks) {
      int kb = ks * 64 + kq * 16;
      bf16x8 a0 = *(bf16x8*)((char*)A_bf + colw * 128 + (kb ^ ((colw & 7) << 4)));
      bf16x8 a1 = *(bf16x8*)((char*)A_bf + arow1 * 128 + (kb ^ ((arow1 & 7) << 4)));
      bf16x8 bb = *(bf16x8*)((char*)B_bf + brow * 128 + (kb ^ ((brow & 7) << 4)));
      acc0 = __builtin_amdgcn_mfma_f32_16x16x32_bf16(a0, bb, acc0, 0, 0, 0);
      acc1 = __builtin_amdgcn_mfma_f32_16x16x32_bf16(a1, bb, acc1, 0, 0, 0);
    }
  }

  float* Yp = xh ? P1 : Y;
  int n = n0 + brow;
  int c0 = kq * 4;
  #pragma unroll
  for (int r = 0; r < 4; ++r) {
    Yp[(size_t)(b * 32 + c0 + r) * NPTS + n] = acc0[r];
    Yp[(size_t)(b * 32 + c0 + r + 16) * NPTS + n] = acc1[r];
  }
}

// ---------------------------------------------------------------------------
__global__ __launch_bounds__(256) void reduce_kernel(
    float* __restrict__ Y, const float* __restrict__ P1) {
  int i = blockIdx.x * 256 + threadIdx.x;   // 262144 float4s
  float4 a = ((const float4*)Y)[i];
  float4 b = ((const float4*)P1)[i];
  a.x += b.x; a.y += b.y; a.z += b.z; a.w += b.w;
  ((float4*)Y)[i] = a;
}

// ---------------------------------------------------------------------------
extern "C" void kernel_launch(void* const* d_in, const int* in_sizes, int n_in,
                              void* d_out, int out_size, void* d_ws, size_t ws_size,
                              hipStream_t stream) {
  const float* u      = (const float*)d_in[0];
  const float* x_in   = (const float*)d_in[1];
  const float* x_out  = (const float*)d_in[2];
  const float* t      = (const float*)d_in[3];
  const float* w_freq = (const float*)d_in[4];
  const float* b_freq = (const float*)d_in[5];
  const float* w1     = (const float*)d_in[6];
  const float* w2     = (const float*)d_in[7];
  float* Y = (float*)d_out;

  unsigned int* E2in  = (unsigned int*)d_ws;           // 1048576 slots
  unsigned int* E2out = E2in + 1048576;                // 1048576
  float* P_uft    = (float*)(E2out + 1048576);         // 2031616 (4 partials)
  float* out_full = P_uft + 2031616;                   // 507904
  float* P1 = P_uft;                                   // reuse (dead after apply)

  prep_kernel<<<2048, 256, 0, stream>>>(x_in, x_out, E2in, E2out);
  uft_kernel<<<1024, 256, 0, stream>>>(u, x_in, E2in, P_uft);
  apply_kernel<<<dim3(32, 8), 512, 0, stream>>>(t, w_freq, b_freq, w1, w2, P_uft, out_full);
  inv_kernel<<<1024, 256, 0, stream>>>(out_full, x_out, E2out, Y, P1);
  reduce_kernel<<<1024, 256, 0, stream>>>(Y, P1);
}

// Round 3
// 76.257 us; speedup vs baseline: 1.4481x; 1.2952x over previous
//
#include <hip/hip_runtime.h>
#include <hip/hip_bf16.h>

// SpectralConv2d: B=8, CIN=COUT=32, N=4096, modes 32x x 31y
// Factorized basis exp(i(th1+th2)) = E1[n,x]*E2[n,y]; E1/E2 bf16 cis tables.
//
// ws layout (4-byte slots):
//   E2in  [b][y][n] : 1048576   (aliased by out_full after uft)
//   E2out [b][y][n] : 1048576
//   E1in  [b][x][n] : 1048576
//   P_uft [s=4][b][x][c][62] : 2031616  (aliased by inv partial P1)
// total 5,177,344 slots = 19.75 MB

#define NPTS 4096
#define TDIM 128
#define TWO_PI 6.283185307179586f

typedef __attribute__((ext_vector_type(8))) short bf16x8;
typedef __attribute__((ext_vector_type(4))) float f32x4;

__device__ __forceinline__ unsigned int pack2(float a, float b) {
  __hip_bfloat162 h = __float22bfloat162_rn(make_float2(a, b));  // v_cvt_pk_bf16_f32
  unsigned int r;
  __builtin_memcpy(&r, &h, 4);
  return r;
}
__device__ __forceinline__ float bflo(unsigned int u) { return __uint_as_float(u << 16); }
__device__ __forceinline__ float bfhi(unsigned int u) { return __uint_as_float(u & 0xFFFF0000u); }

// ---------------------------------------------------------------------------
// Prep: bf16 cis tables. tbl 0: E2in (x_in.y, k2y), 1: E2out (x_out.y, k2y),
// 2: E1in (x_in.x, k1x).  y=31 rows of E2 are zero pad.
__global__ __launch_bounds__(256) void prep_kernel(
    const float* __restrict__ x_in, const float* __restrict__ x_out,
    unsigned int* __restrict__ E2in, unsigned int* __restrict__ E2out,
    unsigned int* __restrict__ E1in) {
  int lin = blockIdx.x * 256 + threadIdx.x;   // 786432 tasks, 4 n each
  int tbl = lin >> 18;
  int rem = lin & 262143;
  int b = rem >> 15;
  int rem2 = rem & 32767;
  int m = rem2 >> 10;
  int n4 = (rem2 & 1023) << 2;
  if (tbl == 2) {
    float k1x = (m < 16) ? (float)m : (float)(m - 32);
    uint4 p;
    unsigned int* pp = &p.x;
    #pragma unroll
    for (int i = 0; i < 4; ++i) {
      float x0 = x_in[(size_t)(b * NPTS + n4 + i) * 2];
      float th = TWO_PI * x0 * k1x;
      pp[i] = pack2(__cosf(th), __sinf(th));
    }
    *(uint4*)&E1in[((b * 32 + m) << 12) + n4] = p;
  } else {
    const float* xs = tbl ? x_out : x_in;
    unsigned int* dst = tbl ? E2out : E2in;
    uint4 p = {0u, 0u, 0u, 0u};
    if (m < 31) {
      float k2y = (m < 16) ? (float)m : (float)(m - 31);
      unsigned int* pp = &p.x;
      #pragma unroll
      for (int i = 0; i < 4; ++i) {
        float x1 = xs[(size_t)(b * NPTS + n4 + i) * 2 + 1];
        float th = TWO_PI * x1 * k2y;
        pp[i] = pack2(__cosf(th), __sinf(th));
      }
    }
    *(uint4*)&dst[((b * 32 + m) << 12) + n4] = p;
  }
}

// ---------------------------------------------------------------------------
// Phase 1 (split-K by 4): per (b,x,s): A = u bf16 [32c x 1024n],
// B rows j=2y+comp from E1*E2 combine (all table-fed, prefetched to regs).
__global__ __launch_bounds__(256) void uft_kernel(
    const float* __restrict__ u, const unsigned int* __restrict__ E1in,
    const unsigned int* __restrict__ E2in, float* __restrict__ P) {
  const int bid = blockIdx.x;        // 1024
  const int b = bid & 7;             // XCD pin
  const int inner = bid >> 3;
  const int x = inner & 31;
  const int s = inner >> 5;
  const int tid = threadIdx.x;
  const int lane = tid & 63, wv = tid >> 6;

  __shared__ __align__(16) unsigned short u_bf[32 * 256];    // 16KB, swizzled
  __shared__ __align__(16) unsigned short bas_bf[64 * 256];  // 32KB, swizzled

  const int oct = tid & 31;   // n-octet owner
  const int yg = tid >> 5;    // 0..7

  const int colw = lane & 15;
  const int kq = lane >> 4;
  const int arow1 = colw + 16;
  const int brow = wv * 16 + colw;

  f32x4 acc0 = {0.f, 0.f, 0.f, 0.f};
  f32x4 acc1 = {0.f, 0.f, 0.f, 0.f};

  float4 pu[4][2];   // u prefetch (32 VGPR)
  uint4 pe2[4][2];   // E2 prefetch (32 VGPR)
  uint4 pe1[2];      // E1 prefetch (8 VGPR)

  auto do_loads = [&](int ch) {
    const int n0 = s * 1024 + ch * 256;
    #pragma unroll
    for (int it = 0; it < 4; ++it) {
      const float4* src = (const float4*)&u[(size_t)(b * 32 + yg + it * 8) * NPTS + n0 + oct * 8];
      pu[it][0] = src[0];
      pu[it][1] = src[1];
    }
    #pragma unroll
    for (int k = 0; k < 4; ++k) {
      const uint4* e2p = (const uint4*)&E2in[((b * 32 + yg + 8 * k) << 12) + n0 + oct * 8];
      pe2[k][0] = e2p[0];
      pe2[k][1] = e2p[1];
    }
    const uint4* e1p = (const uint4*)&E1in[((b * 32 + x) << 12) + n0 + oct * 8];
    pe1[0] = e1p[0];
    pe1[1] = e1p[1];
  };

  do_loads(0);

  for (int ch = 0; ch < 4; ++ch) {
    __syncthreads();   // previous MFMA reads done

    // unpack E1 once per chunk
    float c1v[8], s1v[8];
    {
      unsigned int e1w[8] = {pe1[0].x, pe1[0].y, pe1[0].z, pe1[0].w,
                             pe1[1].x, pe1[1].y, pe1[1].z, pe1[1].w};
      #pragma unroll
      for (int i = 0; i < 8; ++i) { c1v[i] = bflo(e1w[i]); s1v[i] = bfhi(e1w[i]); }
    }

    // stage u -> LDS
    #pragma unroll
    for (int it = 0; it < 4; ++it) {
      int c = yg + it * 8;
      uint4 pw;
      pw.x = pack2(pu[it][0].x, pu[it][0].y);
      pw.y = pack2(pu[it][0].z, pu[it][0].w);
      pw.z = pack2(pu[it][1].x, pu[it][1].y);
      pw.w = pack2(pu[it][1].z, pu[it][1].w);
      *(uint4*)((char*)u_bf + c * 512 + ((oct * 16) ^ ((c & 7) << 4))) = pw;
    }

    // combine basis rows 2y (re), 2y+1 (im):  exp(-i(th1+th2))
    #pragma unroll
    for (int k = 0; k < 4; ++k) {
      int y = yg + 8 * k;
      unsigned int ee[8] = {pe2[k][0].x, pe2[k][0].y, pe2[k][0].z, pe2[k][0].w,
                            pe2[k][1].x, pe2[k][1].y, pe2[k][1].z, pe2[k][1].w};
      float re[8], im[8];
      #pragma unroll
      for (int i = 0; i < 8; ++i) {
        float c2 = bflo(ee[i]), s2 = bfhi(ee[i]);
        re[i] = fmaf(c1v[i], c2, -(s1v[i] * s2));      // cos(th1+th2)
        im[i] = -fmaf(s1v[i], c2, c1v[i] * s2);        // -sin(th1+th2)
      }
      uint4 pr, pi;
      pr.x = pack2(re[0], re[1]); pr.y = pack2(re[2], re[3]);
      pr.z = pack2(re[4], re[5]); pr.w = pack2(re[6], re[7]);
      pi.x = pack2(im[0], im[1]); pi.y = pack2(im[2], im[3]);
      pi.z = pack2(im[4], im[5]); pi.w = pack2(im[6], im[7]);
      int rc = 2 * y, rs = 2 * y + 1;
      int nb = oct * 16;
      *(uint4*)((char*)bas_bf + rc * 512 + (nb ^ ((rc & 7) << 4))) = pr;
      *(uint4*)((char*)bas_bf + rs * 512 + (nb ^ ((rs & 7) << 4))) = pi;
    }

    if (ch < 3) do_loads(ch + 1);   // overlap with MFMA phase
    __syncthreads();

    #pragma unroll
    for (int ks = 0; ks < 8; ++ks) {
      int kb = ks * 64 + kq * 16;
      bf16x8 a0 = *(bf16x8*)((char*)u_bf + colw * 512 + (kb ^ ((colw & 7) << 4)));
      bf16x8 a1 = *(bf16x8*)((char*)u_bf + arow1 * 512 + (kb ^ ((arow1 & 7) << 4)));
      bf16x8 bb = *(bf16x8*)((char*)bas_bf + brow * 512 + (kb ^ ((brow & 7) << 4)));
      acc0 = __builtin_amdgcn_mfma_f32_16x16x32_bf16(a0, bb, acc0, 0, 0, 0);
      acc1 = __builtin_amdgcn_mfma_f32_16x16x32_bf16(a1, bb, acc1, 0, 0, 0);
    }
  }

  int j = brow, y = j >> 1, comp = j & 1;
  if (y < 31) {
    int c0 = kq * 4;
    float* Ps = P + (size_t)s * 507904;
    #pragma unroll
    for (int r = 0; r < 4; ++r) {
      Ps[(size_t)((b * 32 + x) * 32 + c0 + r) * 62 + y * 2 + comp] = acc0[r];
      Ps[(size_t)((b * 32 + x) * 32 + c0 + r + 16) * 62 + y * 2 + comp] = acc1[r];
    }
  }
}

// ---------------------------------------------------------------------------
// Phase 2: mode-wise complex matmul + emb + Hermitian extension (fused 4-way reduce).
__global__ __launch_bounds__(512) void apply_kernel(
    const float* __restrict__ t, const float* __restrict__ w_freq,
    const float* __restrict__ b_freq, const float* __restrict__ w1,
    const float* __restrict__ w2, const float* __restrict__ P,
    float* __restrict__ out_full) {
  const int x = blockIdx.x, b = blockIdx.y;
  const int tid = threadIdx.x;
  const int m1 = x & 15, sel = x >> 4;

  __shared__ float uf_s[32][16][2];
  __shared__ float emb_s[16][2];

  for (int idx = tid; idx < 32 * 32; idx += 512) {
    int i = idx >> 5, r = idx & 31;
    size_t base = (size_t)((b * 32 + x) * 32 + i) * 62 + r;
    uf_s[i][r >> 1][r & 1] = P[base] + P[base + 507904] + P[base + 2 * 507904] + P[base + 3 * 507904];
  }
  if (tid < 32) {
    int y = tid >> 1, p = tid & 1;
    int jj = ((m1 * 16 + y) * 2 + sel) * 2 + p;
    float s = b_freq[jj];
    for (int k = 0; k < TDIM; ++k) s += t[b * TDIM + k] * w_freq[k * 1024 + jj];
    emb_s[y][p] = s;
  }
  __syncthreads();

  int o = tid >> 4, y = tid & 15;
  const float* wsel = sel ? w2 : w1;
  float fr = 0.f, fi = 0.f;
  #pragma unroll 4
  for (int i = 0; i < 32; ++i) {
    float2 w = *(const float2*)&wsel[(size_t)(((i * 32 + o) * 16 + m1) * 16 + y) * 2];
    float ur = uf_s[i][y][0], ui = uf_s[i][y][1];
    fr += ur * w.x - ui * w.y;
    fi += ur * w.y + ui * w.x;
  }
  float er = emb_s[y][0], ei = emb_s[y][1];
  float orr = fr * er - fi * ei;
  float oii = fr * ei + fi * er;
  size_t mo = (size_t)((b * 32 + x) * 32 + o) * 62 + y * 2;
  out_full[mo] = orr;
  out_full[mo + 1] = oii;
  if (y > 0) {
    size_t cj = (size_t)((b * 32 + (31 - x)) * 32 + o) * 62 + (31 - y) * 2;
    out_full[cj] = orr;
    out_full[cj + 1] = -oii;
  }
}

// ---------------------------------------------------------------------------
// Phase 3 (x split by 2): 16 x-phases; A prefetched to regs, B from E2out(LDS)*E1.
__global__ __launch_bounds__(256) void inv_kernel(
    const float* __restrict__ out_full, const float* __restrict__ x_out,
    const unsigned int* __restrict__ E2out, float* __restrict__ Y,
    float* __restrict__ P1) {
  const int bid = blockIdx.x;        // 1024
  const int b = bid & 7;
  const int inner = bid >> 3;
  const int nt = inner & 63;
  const int xh = inner >> 6;
  const int n0 = nt * 64;
  const int tid = threadIdx.x;
  const int lane = tid & 63, wv = tid >> 6;

  __shared__ __align__(16) unsigned short A_bf[32 * 64];
  __shared__ __align__(16) unsigned short B_bf[64 * 64];
  __shared__ unsigned int e2s[32 * 65];

  #pragma unroll
  for (int it = 0; it < 8; ++it) {
    int idx = tid + it * 256;
    int y = idx >> 6, n = idx & 63;
    e2s[y * 65 + n] = E2out[((b * 32 + y) << 12) + n0 + n];
  }

  const int bn = tid >> 2;       // B-row n per thread
  const int ygr = tid & 3;       // y-group
  const float x0 = x_out[(size_t)(b * NPTS + n0 + bn) * 2];

  const int colw = lane & 15;
  const int kq = lane >> 4;
  const int arow1 = colw + 16;
  const int brow = wv * 16 + colw;

  f32x4 acc0 = {0.f, 0.f, 0.f, 0.f};
  f32x4 acc1 = {0.f, 0.f, 0.f, 0.f};

  float2 pA[4];
  auto loadA = [&](int xx) {
    #pragma unroll
    for (int it = 0; it < 4; ++it) {
      int idx = tid + it * 256;
      int c = idx >> 5, p = idx & 31;
      pA[it] = (p < 31)
          ? *(const float2*)&out_full[(size_t)((b * 32 + xx) * 32 + c) * 62 + p * 2]
          : make_float2(0.f, 0.f);
    }
  };
  loadA(xh * 16);
  __syncthreads();   // e2s ready

  for (int xi = 0; xi < 16; ++xi) {
    const int x = xh * 16 + xi;
    const float k1x = (x < 16) ? (float)x : (float)(x - 32);
    float th1 = TWO_PI * x0 * k1x;
    float c1 = __cosf(th1), s1 = __sinf(th1);

    __syncthreads();   // prev MFMA reads done

    // stage A from prefetched regs
    #pragma unroll
    for (int it = 0; it < 4; ++it) {
      int idx = tid + it * 256;
      int c = idx >> 5, p = idx & 31;
      *(unsigned int*)((char*)A_bf + c * 128 + ((p * 4) ^ ((c & 7) << 4))) =
          pack2(pA[it].x, pA[it].y);
    }
    // stage B: row bn, 8 y's;  exp(+i(th1+th2)) -> (cos, -sin)
    #pragma unroll
    for (int k = 0; k < 8; ++k) {
      int y = ygr * 8 + k;
      unsigned int e = e2s[y * 65 + bn];
      float c2 = bflo(e), s2 = bfhi(e);
      float re = fmaf(c1, c2, -(s1 * s2));
      float im = -fmaf(s1, c2, c1 * s2);
      *(unsigned int*)((char*)B_bf + bn * 128 + ((y * 4) ^ ((bn & 7) << 4))) = pack2(re, im);
    }
    if (xi < 15) loadA(x + 1);   // overlap with MFMA phase
    __syncthreads();

    #pragma unroll
    for (int ks = 0; ks < 2; ++ks) {
      int kb = ks * 64 + kq * 16;
      bf16x8 a0 = *(bf16x8*)((char*)A_bf + colw * 128 + (kb ^ ((colw & 7) << 4)));
      bf16x8 a1 = *(bf16x8*)((char*)A_bf + arow1 * 128 + (kb ^ ((arow1 & 7) << 4)));
      bf16x8 bb = *(bf16x8*)((char*)B_bf + brow * 128 + (kb ^ ((brow & 7) << 4)));
      acc0 = __builtin_amdgcn_mfma_f32_16x16x32_bf16(a0, bb, acc0, 0, 0, 0);
      acc1 = __builtin_amdgcn_mfma_f32_16x16x32_bf16(a1, bb, acc1, 0, 0, 0);
    }
  }

  float* Yp = xh ? P1 : Y;
  int n = n0 + brow;
  int c0 = kq * 4;
  #pragma unroll
  for (int r = 0; r < 4; ++r) {
    Yp[(size_t)(b * 32 + c0 + r) * NPTS + n] = acc0[r];
    Yp[(size_t)(b * 32 + c0 + r + 16) * NPTS + n] = acc1[r];
  }
}

// ---------------------------------------------------------------------------
__global__ __launch_bounds__(256) void reduce_kernel(
    float* __restrict__ Y, const float* __restrict__ P1) {
  int i = blockIdx.x * 256 + threadIdx.x;   // 262144 float4s
  float4 a = ((const float4*)Y)[i];
  float4 b = ((const float4*)P1)[i];
  a.x += b.x; a.y += b.y; a.z += b.z; a.w += b.w;
  ((float4*)Y)[i] = a;
}

// ---------------------------------------------------------------------------
extern "C" void kernel_launch(void* const* d_in, const int* in_sizes, int n_in,
                              void* d_out, int out_size, void* d_ws, size_t ws_size,
                              hipStream_t stream) {
  const float* u      = (const float*)d_in[0];
  const float* x_in   = (const float*)d_in[1];
  const float* x_out  = (const float*)d_in[2];
  const float* t      = (const float*)d_in[3];
  const float* w_freq = (const float*)d_in[4];
  const float* b_freq = (const float*)d_in[5];
  const float* w1     = (const float*)d_in[6];
  const float* w2     = (const float*)d_in[7];
  float* Y = (float*)d_out;

  unsigned int* E2in  = (unsigned int*)d_ws;           // 1048576 slots
  unsigned int* E2out = E2in + 1048576;                // 1048576
  unsigned int* E1in  = E2out + 1048576;               // 1048576
  float* P_uft    = (float*)(E1in + 1048576);          // 2031616 (4 partials)
  float* out_full = (float*)E2in;                      // alias: E2in dead after uft
  float* P1 = P_uft;                                   // alias: P dead after apply

  prep_kernel<<<3072, 256, 0, stream>>>(x_in, x_out, E2in, E2out, E1in);
  uft_kernel<<<1024, 256, 0, stream>>>(u, E1in, E2in, P_uft);
  apply_kernel<<<dim3(32, 8), 512, 0, stream>>>(t, w_freq, b_freq, w1, w2, P_uft, out_full);
  inv_kernel<<<1024, 256, 0, stream>>>(out_full, x_out, E2out, Y, P1);
  reduce_kernel<<<1024, 256, 0, stream>>>(Y, P1);
}